// Round 12
// baseline (303.862 us; speedup 1.0000x reference)
//
#include <hip/hip_runtime.h>
#include <hip/hip_bf16.h>

// ---------------------------------------------------------------------------
// EncoderLayer: B=2 S=2048 D=768 H=12 DK=64 DFF=3072
// fp32 inputs/outputs; bf16 MFMA compute with fp32 accumulate.
// ---------------------------------------------------------------------------

typedef short short8 __attribute__((ext_vector_type(8)));
typedef float floatx4 __attribute__((ext_vector_type(4)));
typedef unsigned short ushort_t;
typedef ushort_t ushort4_t __attribute__((ext_vector_type(4)));

#define B_ 2
#define S_ 2048
#define D_ 768
#define H_ 12
#define DK_ 64
#define DFF_ 3072
#define M_ (B_ * S_)          // 4096 rows
#define RS_ (3 * D_)          // 2304 qkv row stride

#define LOG2E 1.44269504f
#define FMAX_SHIFT 16.0f      // fixed softmax shift (scores ~N(0,1), max ~6)

__device__ __forceinline__ float bf2f(ushort_t h) {
  union { unsigned int u; float f; } v; v.u = ((unsigned int)h) << 16; return v.f;
}
__device__ __forceinline__ ushort_t f2bf(float f) {
  union { float f; unsigned int u; } v; v.f = f;
  unsigned int u = v.u;
  unsigned int r = (u + 0x7fffu + ((u >> 16) & 1u)) >> 16;
  return (ushort_t)r;
}

// ---------------------------------------------------------------------------
// ALL prep in ONE launch:
//  [0,2304):      4 DxD transposes (wq,wk,wv->wTqkv; wo->woT)
//  [2304,4608):   w1 [768][3072] -> w1T
//  [4608,6912):   w2 [3072][768] -> w2T
//  [6912,8960):   mask int32 [q][kp] -> bias bf16 [q][kp-PERMUTED], log2 dom.
//  [8960,12032):  x fp32 -> xb bf16
//  [12032,12041): concat bq|bk|bv -> bqkv fp32
// kp-permutation per 64 window: pos f*32+lq*8+j holds kp=32f+16(j>>2)+4lq+(j&3)
// ---------------------------------------------------------------------------
__global__ __launch_bounds__(256) void prep_all(
    const float* __restrict__ wq, const float* __restrict__ wk,
    const float* __restrict__ wv, const float* __restrict__ wo,
    const float* __restrict__ w1, const float* __restrict__ w2,
    ushort_t* __restrict__ wTqkv, ushort_t* __restrict__ woT,
    ushort_t* __restrict__ w1T, ushort_t* __restrict__ w2T,
    const int* __restrict__ mask, ushort_t* __restrict__ maskp,
    const float* __restrict__ x, ushort_t* __restrict__ xb,
    const float* __restrict__ bq, const float* __restrict__ bk,
    const float* __restrict__ bv, float* __restrict__ bqkv) {
  __shared__ ushort_t t[32][33];
  const int blk = blockIdx.x, tid = threadIdx.x;
  if (blk < 6912) {
    const float* in; ushort_t* out; int K, N, bx, by;
    if (blk < 2304) {
      const int z = blk / 576, rr = blk % 576;
      in = (z == 0) ? wq : (z == 1) ? wk : (z == 2) ? wv : wo;
      out = (z < 3) ? (wTqkv + (size_t)z * D_ * D_) : woT;
      K = D_; N = D_; bx = rr % 24; by = rr / 24;
    } else if (blk < 4608) {
      const int rr = blk - 2304;
      in = w1; out = w1T; K = D_; N = DFF_; bx = rr % 96; by = rr / 96;
    } else {
      const int rr = blk - 4608;
      in = w2; out = w2T; K = DFF_; N = D_; bx = rr % 24; by = rr / 24;
    }
    const int nt = bx * 32, kt = by * 32;
    const int tx = tid & 31, ty = tid >> 5;
#pragma unroll
    for (int i = 0; i < 4; i++)
      t[ty + i * 8][tx] = f2bf(in[(size_t)(kt + ty + i * 8) * N + nt + tx]);
    __syncthreads();
#pragma unroll
    for (int i = 0; i < 4; i++)
      out[(size_t)(nt + ty + i * 8) * K + kt + tx] = t[tx][ty + i * 8];
  } else if (blk < 8960) {
    const int tt = (blk - 6912) * 256 + tid;        // one 8-elem chunk each
    const int q = tt >> 8;
    const int cc = tt & 255;
    const int k0 = (cc >> 3) * 64;
    const int g = cc & 7, f = g >> 2, lq = g & 3;
    const int* mrow = mask + (size_t)q * S_ + k0;
    const ushort_t cm = f2bf(-1.4427e9f);
    const ushort_t cu = f2bf(-FMAX_SHIFT * LOG2E);
    short8 o;
#pragma unroll
    for (int n2 = 0; n2 < 2; n2++)
#pragma unroll
      for (int r = 0; r < 4; r++) {
        const int kpl = 32 * f + 16 * n2 + 4 * lq + r;
        o[n2 * 4 + r] = (short)((mrow[kpl] == 0) ? cm : cu);
      }
    *(short8*)(maskp + (size_t)q * S_ + k0 + g * 8) = o;
  } else if (blk < 12032) {
    const int i = ((blk - 8960) * 256 + tid) * 4;
#pragma unroll
    for (int j = 0; j < 4; j++) xb[i + j] = f2bf(x[i + j]);
  } else {
    const int i = (blk - 12032) * 256 + tid;
    if (i < 3 * D_)
      bqkv[i] = (i < D_) ? bq[i] : (i < 2 * D_ ? bk[i - D_] : bv[i - 2 * D_]);
  }
}

// ---------------------------------------------------------------------------
// GEMM: BM=128, BN in {64,128}, BK=32, double-buffered LDS staging,
// XCD-aware 1-D grid decode. Z = split-K factor (1, 2 or 4); Z>1 writes bf16
// partial z to Cv + z*M*N (bias applied in combine).
// VOUT=true (QKV only): for n >= 2*D_ the result is V -> written directly to
// vt[bh][d][kp-PERMUTED] (fused vtrans); qkv V-section not written.
// ---------------------------------------------------------------------------
template <int BN, int Z, bool VOUT>
__global__ __launch_bounds__(256) void gemm_bt_t(
    const ushort_t* __restrict__ A, const ushort_t* __restrict__ Bt,
    const float* __restrict__ bias, void* __restrict__ Cv,
    ushort_t* __restrict__ vtout,
    int M, int N, int K, int relu, int qcols, float qscale) {
  constexpr int WN = (BN == 128) ? 2 : 1;
  constexpr int WM = 4 / WN;
  constexpr int FI = 128 / WM / 16;
  constexpr int FJ = BN / WN / 16;
  constexpr bool SPLIT = (Z > 1);
  __shared__ __align__(16) ushort_t Al[2][128 * 32];
  __shared__ __align__(16) ushort_t Bl[2][BN * 32];
  const int tid = threadIdx.x;
  const int w = tid >> 6, lane = tid & 63;
  const int wm = (WN == 2) ? (w >> 1) : w;
  const int wn = (WN == 2) ? (w & 1) : 0;
  const int lq = lane >> 4, lr = lane & 15;

  // XCD-aware decode
  const int NT_n = N / BN;
  const int mg = M >> 10;                 // m-tiles per XCD (M/128/8)
  const int lin = blockIdx.x;
  const int xcd = lin & 7, idx = lin >> 3;
  const int m_t = xcd * mg + idx / (NT_n * Z);
  const int rem = idx % (NT_n * Z);
  const int n_t = rem % NT_n;
  const int z   = rem / NT_n;
  const int m0 = m_t * 128, n0 = n_t * BN;

  int kBeg = 0, kEnd = K;
  if (SPLIT) { const int part = K / Z; kBeg = z * part; kEnd = kBeg + part; }
  const int NT = (kEnd - kBeg) / 32;

  auto stage = [&](int kt, int s) {
    const int k0 = kBeg + kt * 32;
#pragma unroll
    for (int i = 0; i < 2; i++) {
      const int base = (w * 2 + i) * 512;
      const int e = base + lane * 8;
      const int row = e >> 5, col = e & 31;
      __builtin_amdgcn_global_load_lds(
          (const __attribute__((address_space(1))) void*)(A + (size_t)(m0 + row) * K + k0 + col),
          (__attribute__((address_space(3))) void*)(&Al[s][base]), 16, 0, 0);
    }
#pragma unroll
    for (int i = 0; i < BN / 64; i++) {
      const int base = (w * (BN / 64) + i) * 512;
      const int e = base + lane * 8;
      const int row = e >> 5, col = e & 31;
      __builtin_amdgcn_global_load_lds(
          (const __attribute__((address_space(1))) void*)(Bt + (size_t)(n0 + row) * K + k0 + col),
          (__attribute__((address_space(3))) void*)(&Bl[s][base]), 16, 0, 0);
    }
  };

  floatx4 acc[FI][FJ];
#pragma unroll
  for (int i = 0; i < FI; i++)
#pragma unroll
    for (int j = 0; j < FJ; j++) acc[i][j] = (floatx4){0.f, 0.f, 0.f, 0.f};

  stage(0, 0);
  for (int kt = 0; kt < NT; kt++) {
    const int s = kt & 1;
    __syncthreads();                 // stage(kt) landed; buf s^1 reads done
    if (kt + 1 < NT) stage(kt + 1, s ^ 1);

    short8 af[FI], bf[FJ];
#pragma unroll
    for (int i = 0; i < FI; i++)
      af[i] = *(const short8*)&Al[s][(wm * (FI * 16) + i * 16 + lr) * 32 + lq * 8];
#pragma unroll
    for (int j = 0; j < FJ; j++)
      bf[j] = *(const short8*)&Bl[s][(wn * (FJ * 16) + j * 16 + lr) * 32 + lq * 8];
#pragma unroll
    for (int i = 0; i < FI; i++)
#pragma unroll
      for (int j = 0; j < FJ; j++)
        acc[i][j] = __builtin_amdgcn_mfma_f32_16x16x32_bf16(af[i], bf[j], acc[i][j], 0, 0, 0);
  }

#pragma unroll
  for (int i = 0; i < FI; i++) {
    const int m = m0 + wm * (FI * 16) + i * 16 + lq * 4;
#pragma unroll
    for (int j = 0; j < FJ; j++) {
      const int n = n0 + wn * (FJ * 16) + j * 16 + lr;
      if (SPLIT) {
        ushort_t* P = (ushort_t*)Cv + (size_t)z * M * N;
#pragma unroll
        for (int r = 0; r < 4; r++)
          P[(size_t)(m + r) * N + n] = f2bf(acc[i][j][r]);
      } else if (VOUT && n >= 2 * D_) {
        // fused vtrans: element (kp=m+r, d) of head h -> vt permuted layout
        const int h = (n - 2 * D_) >> 6, d = (n - 2 * D_) & 63;
        const int bh = (m >> 11) * H_ + h;
        const int kp = m & (S_ - 1);
        const int kw = kp & 63;     // kw&3==0 since m%4==0
        const int pos = (kp & ~63) + ((kw >> 5) << 5) + (((kw >> 2) & 3) << 3)
                      + (((kw >> 4) & 1) << 2);
        const float bv = bias[n];
        ushort4_t o;
#pragma unroll
        for (int r = 0; r < 4; r++) o[r] = f2bf(acc[i][j][r] + bv);
        *(ushort4_t*)(vtout + ((size_t)bh * DK_ + d) * S_ + pos) = o;
      } else {
        const float bv = bias[n];
#pragma unroll
        for (int r = 0; r < 4; r++) {
          float v = acc[i][j][r] + bv;
          if (n < qcols) v *= qscale;
          if (relu) v = v > 0.f ? v : 0.f;
          ((ushort_t*)Cv)[(size_t)(m + r) * N + n] = f2bf(v);
        }
      }
    }
  }
}

// ---------------------------------------------------------------------------
// Flash attention v9 — 2x2 wave split (q-half x kp-half); fixed-shift softmax;
// mask bias loaded DIRECTLY from global into regs (prefetched 1 tile ahead),
// folded into MFMA C-init; li via all-ones MFMA. LDS stages only K + V
// (2 x 16 KB buffers = 32 KB). Cross-wk reduction via LDS at the end.
// Grid 768 (bh-fastest), 4 waves.
// ---------------------------------------------------------------------------
__global__ __launch_bounds__(256, 3) void flash_attn(
    const ushort_t* __restrict__ qkv, const ushort_t* __restrict__ vt,
    const ushort_t* __restrict__ maskp, ushort_t* __restrict__ ctx) {
  __shared__ __align__(16) ushort_t lds[2][2][64 * 64];   // [buf][K,V] 32 KB
  const int tid = threadIdx.x;
  const int w = tid >> 6, lane = tid & 63;
  const int wq = w >> 1, wk = w & 1;
  const int lq = lane >> 4, lr = lane & 15;
  const int blk = blockIdx.x;
  const int bh = blk % (B_ * H_), qb = blk / (B_ * H_);
  const int b = bh / H_, h = bh % H_;
  const int q0 = qb * 64;
  const ushort_t* qbase = qkv + (size_t)(b * S_) * RS_ + h * DK_;
  const ushort_t* kbase = qbase + D_;
  const ushort_t* vtb   = vt + (size_t)bh * DK_ * S_;
  // per-lane global bias pointer: row q0+wq*32+lr (+16 rows for qf=1),
  // chunk (4wk+lq) of each 64-kp window
  const ushort_t* mrow = maskp + (size_t)(q0 + wq * 32 + lr) * S_ + (4 * wk + lq) * 8;

  // Q fragments: wave covers q = q0 + wq*32 + qf*16 + lr (pre-scaled log2e/8)
  short8 qfr[2][2];
#pragma unroll
  for (int qf = 0; qf < 2; qf++)
#pragma unroll
    for (int f = 0; f < 2; f++)
      qfr[qf][f] = *(const short8*)(
          qbase + (size_t)(q0 + wq * 32 + qf * 16 + lr) * RS_ + f * 32 + lq * 8);

  auto stage = [&](int k0, int s) {
#pragma unroll
    for (int i = 0; i < 2; i++) {
      const int id = i * 256 + tid;
      const int row = id >> 3;
      const int cc = ((id & 7) ^ (row & 7)) * 8;
      const int dbase = (i * 256 + w * 64) * 8;    // wave-uniform LDS base
      __builtin_amdgcn_global_load_lds(
          (const __attribute__((address_space(1))) void*)(kbase + (size_t)(k0 + row) * RS_ + cc),
          (__attribute__((address_space(3))) void*)(&lds[s][0][dbase]), 16, 0, 0);
      __builtin_amdgcn_global_load_lds(
          (const __attribute__((address_space(1))) void*)(vtb + (size_t)row * S_ + k0 + cc),
          (__attribute__((address_space(3))) void*)(&lds[s][1][dbase]), 16, 0, 0);
    }
  };

  floatx4 oacc[2][4], oli[2];
#pragma unroll
  for (int qf = 0; qf < 2; qf++) {
    oli[qf] = (floatx4){0.f, 0.f, 0.f, 0.f};
#pragma unroll
    for (int dt = 0; dt < 4; dt++) oacc[qf][dt] = (floatx4){0.f, 0.f, 0.f, 0.f};
  }
  short8 ones;
#pragma unroll
  for (int j = 0; j < 8; j++) ones[j] = (short)0x3F80;   // bf16 1.0

  short8 bb[2], bbn[2];
#pragma unroll
  for (int qf = 0; qf < 2; qf++)
    bb[qf] = *(const short8*)(mrow + (size_t)qf * 16 * S_);

  stage(0, 0);
  __syncthreads();

  const int sw8 = lr & 7;
  const int c0 = (lq ^ sw8) * 8;              // K chunk, k-half 0
  const int c1 = ((4 + lq) ^ sw8) * 8;        // K chunk, k-half 1
  const int cW = ((4 * wk + lq) ^ sw8) * 8;   // wave's kp-window chunk (V)

  constexpr int NT = S_ / 64;
  for (int t = 0; t < NT; t++) {
    const int s = t & 1;
    if (t + 1 < NT) {
      stage((t + 1) * 64, s ^ 1);
#pragma unroll
      for (int qf = 0; qf < 2; qf++)
        bbn[qf] = *(const short8*)(mrow + (size_t)qf * 16 * S_ + (t + 1) * 64);
    }

    const ushort_t* kl = &lds[s][0][0];
    const ushort_t* vl = &lds[s][1][0];

    // mask bias as MFMA C-init: bb[4*n2+r] -> sacc[n2][r]
    floatx4 sacc[2][2];
#pragma unroll
    for (int qf = 0; qf < 2; qf++)
#pragma unroll
      for (int n2 = 0; n2 < 2; n2++)
#pragma unroll
        for (int r = 0; r < 4; r++)
          sacc[qf][n2][r] = bf2f((ushort_t)bb[qf][n2 * 4 + r]);

    // QK^T: wave's kp strips (2wk+n2)
#pragma unroll
    for (int n2 = 0; n2 < 2; n2++) {
      const int krow = ((2 * wk + n2) * 16 + lr) * 64;
      short8 a0 = *(const short8*)(kl + krow + c0);
      short8 a1 = *(const short8*)(kl + krow + c1);
#pragma unroll
      for (int qf = 0; qf < 2; qf++) {
        sacc[qf][n2] = __builtin_amdgcn_mfma_f32_16x16x32_bf16(a0, qfr[qf][0], sacc[qf][n2], 0, 0, 0);
        sacc[qf][n2] = __builtin_amdgcn_mfma_f32_16x16x32_bf16(a1, qfr[qf][1], sacc[qf][n2], 0, 0, 0);
      }
    }

    // p = exp2(s) (bias already inside); pack into PV B-fragments
    short8 pf[2];
#pragma unroll
    for (int qf = 0; qf < 2; qf++) {
      union { __hip_bfloat162 h2[4]; short8 v; } u;
#pragma unroll
      for (int jj = 0; jj < 4; jj++) {
        const int e0 = jj * 2, e1 = jj * 2 + 1;
        float2 p2;
        p2.x = __builtin_amdgcn_exp2f(sacc[qf][e0 >> 2][e0 & 3]);
        p2.y = __builtin_amdgcn_exp2f(sacc[qf][e1 >> 2][e1 & 3]);
        u.h2[jj] = __float22bfloat162_rn(p2);
      }
      pf[qf] = u.v;
    }

    // PV (O^T) + li via ones-MFMA
#pragma unroll
    for (int dt = 0; dt < 4; dt++) {
      const short8 vfr = *(const short8*)(vl + (dt * 16 + lr) * 64 + cW);
#pragma unroll
      for (int qf = 0; qf < 2; qf++)
        oacc[qf][dt] = __builtin_amdgcn_mfma_f32_16x16x32_bf16(vfr, pf[qf], oacc[qf][dt], 0, 0, 0);
    }
#pragma unroll
    for (int qf = 0; qf < 2; qf++)
      oli[qf] = __builtin_amdgcn_mfma_f32_16x16x32_bf16(ones, pf[qf], oli[qf], 0, 0, 0);

    if (t + 1 < NT) {
      bb[0] = bbn[0];
      bb[1] = bbn[1];
    }
    __syncthreads();
  }

  // cross-wk pair reduction via LDS (lane-matched; stride 37 spreads banks)
  float* ex = (float*)&lds[0][0][0];     // [2 wq][64 lane][37] = 18.9 KB
  if (wk == 1) {
    float* dst = ex + (size_t)(wq * 64 + lane) * 37;
#pragma unroll
    for (int qf = 0; qf < 2; qf++)
#pragma unroll
      for (int dt = 0; dt < 4; dt++)
#pragma unroll
        for (int r = 0; r < 4; r++)
          dst[qf * 16 + dt * 4 + r] = oacc[qf][dt][r];
    dst[32] = oli[0][0];
    dst[33] = oli[1][0];
  }
  __syncthreads();
  if (wk == 0) {
    const float* src = ex + (size_t)(wq * 64 + lane) * 37;
#pragma unroll
    for (int qf = 0; qf < 2; qf++)
#pragma unroll
      for (int dt = 0; dt < 4; dt++)
#pragma unroll
        for (int r = 0; r < 4; r++)
          oacc[qf][dt][r] += src[qf * 16 + dt * 4 + r];
    const float inv0 = 1.f / (oli[0][0] + src[32] + 1e-30f);
    const float inv1 = 1.f / (oli[1][0] + src[33] + 1e-30f);
#pragma unroll
    for (int qf = 0; qf < 2; qf++) {
      const float inv = qf ? inv1 : inv0;
      const size_t row = (size_t)(b * S_ + q0 + wq * 32 + qf * 16 + lr) * D_ + h * DK_;
#pragma unroll
      for (int dt = 0; dt < 4; dt++) {
        ushort4_t o;
#pragma unroll
        for (int r = 0; r < 4; r++) o[r] = f2bf(oacc[qf][dt][r] * inv);
        *(ushort4_t*)(ctx + row + dt * 16 + lq * 4) = o;
      }
    }
  }
}

// ---------------------------------------------------------------------------
// out = alpha * (v - mean)/(std_unbiased + eps) + beta, row = 768,
// where v = x + (sum_{p<NP} P[p] + colbias), P bf16 split-K partials at
// stride M*D. XF: x fp32 (else bf16). OF: out fp32 (else bf16).
// ---------------------------------------------------------------------------
template <int NP, bool XF, bool OF>
__global__ __launch_bounds__(256) void add_ln_comb(
    const void* __restrict__ xv, const ushort_t* __restrict__ P,
    const float* __restrict__ cb,
    const float* __restrict__ alpha, const float* __restrict__ beta,
    void* __restrict__ outv) {
  const int row = blockIdx.x, tid = threadIdx.x;
  const int w = tid >> 6, lane = tid & 63;
  __shared__ float red[8];
  float v[3];
#pragma unroll
  for (int i = 0; i < 3; i++) {
    const int c = tid + i * 256;
    const size_t idx = (size_t)row * D_ + c;
    float xv_;
    if (XF) xv_ = ((const float*)xv)[idx];
    else    xv_ = bf2f(((const ushort_t*)xv)[idx]);
    float ps = cb[c];
#pragma unroll
    for (int p = 0; p < NP; p++) ps += bf2f(P[idx + (size_t)p * M_ * D_]);
    v[i] = xv_ + ps;
  }
  float s = v[0] + v[1] + v[2];
#pragma unroll
  for (int off = 1; off < 64; off <<= 1) s += __shfl_xor(s, off);
  if (lane == 0) red[w] = s;
  __syncthreads();
  const float mean = (red[0] + red[1] + red[2] + red[3]) / (float)D_;
  float d = 0.f;
#pragma unroll
  for (int i = 0; i < 3; i++) { const float t = v[i] - mean; d += t * t; }
#pragma unroll
  for (int off = 1; off < 64; off <<= 1) d += __shfl_xor(d, off);
  if (lane == 0) red[4 + w] = d;
  __syncthreads();
  const float var = (red[4] + red[5] + red[6] + red[7]) / (float)(D_ - 1);
  const float inv = 1.f / (sqrtf(var) + 1e-6f);
  const float a = alpha[0] * inv, bt = beta[0];
#pragma unroll
  for (int i = 0; i < 3; i++) {
    const int c = tid + i * 256;
    const float o = a * (v[i] - mean) + bt;
    if (OF) ((float*)outv)[(size_t)row * D_ + c] = o;
    else    ((ushort_t*)outv)[(size_t)row * D_ + c] = f2bf(o);
  }
}

// ---------------------------------------------------------------------------
// launch
// ---------------------------------------------------------------------------
extern "C" void kernel_launch(void* const* d_in, const int* in_sizes, int n_in,
                              void* d_out, int out_size, void* d_ws, size_t ws_size,
                              hipStream_t stream) {
  const float* x   = (const float*)d_in[0];
  const float* wq  = (const float*)d_in[1];
  const float* bq  = (const float*)d_in[2];
  const float* wk  = (const float*)d_in[3];
  const float* bk  = (const float*)d_in[4];
  const float* wv  = (const float*)d_in[5];
  const float* bv  = (const float*)d_in[6];
  const float* wo  = (const float*)d_in[7];
  const float* bo  = (const float*)d_in[8];
  const float* w1  = (const float*)d_in[9];
  const float* b1  = (const float*)d_in[10];
  const float* w2  = (const float*)d_in[11];
  const float* b2  = (const float*)d_in[12];
  const float* a1  = (const float*)d_in[13];
  const float* be1 = (const float*)d_in[14];
  const float* a2  = (const float*)d_in[15];
  const float* be2 = (const float*)d_in[16];
  const int*   msk = (const int*)d_in[17];

  // workspace layout in ushort units; all offsets multiple of 8 (16B aligned)
  const size_t E_xb    = 0;
  const size_t E_wTqkv = E_xb    + (size_t)M_ * D_;
  const size_t E_woT   = E_wTqkv + (size_t)3 * D_ * D_;
  const size_t E_w1T   = E_woT   + (size_t)D_ * D_;
  const size_t E_w2T   = E_w1T   + (size_t)DFF_ * D_;
  const size_t E_bqkv  = E_w2T   + (size_t)D_ * DFF_;
  const size_t E_qkv   = E_bqkv  + (size_t)2 * 3 * D_;
  const size_t E_ctx   = E_qkv   + (size_t)M_ * 3 * D_;
  const size_t E_attn  = E_ctx   + (size_t)M_ * D_;
  const size_t E_x1    = E_attn  + (size_t)M_ * D_;
  const size_t E_h1    = E_x1    + (size_t)M_ * D_;       // h1 [M][DFF] (12.58M)
  const size_t E_ff    = E_h1    + (size_t)M_ * DFF_;
  const size_t E_total = E_ff    + (size_t)M_ * D_;
  if (ws_size < E_total * sizeof(ushort_t)) return;

  ushort_t* ws    = (ushort_t*)d_ws;
  ushort_t* xb    = ws + E_xb;
  ushort_t* wTqkv = ws + E_wTqkv;
  ushort_t* woT   = ws + E_woT;
  ushort_t* w1T   = ws + E_w1T;
  ushort_t* w2T   = ws + E_w2T;
  float*    bqkv  = (float*)(ws + E_bqkv);
  ushort_t* qkv   = ws + E_qkv;
  ushort_t* ctx   = ws + E_ctx;
  ushort_t* x1    = ws + E_x1;
  ushort_t* h1    = ws + E_h1;
  // Overlays (lifetimes disjoint):
  //  maskp (4.19M) + vt (3.15M) live in h1 region until flash done.
  //  Pattn (4 x M x D bf16 = 12.58M ushorts) = h1 region after flash,
  //    dead once FF1 writes h1.
  //  Pff2 (12.58M ushorts) = qkv+ctx region after both dead.
  ushort_t* maskp = ws + E_h1;
  ushort_t* vt    = ws + E_h1 + (size_t)S_ * S_;
  ushort_t* Pattn = ws + E_h1;
  ushort_t* Pff2  = ws + E_qkv;

  const float SCALE_Q = 0.125f * LOG2E;   // log2-domain scores

  prep_all<<<12041, 256, 0, stream>>>(wq, wk, wv, wo, w1, w2,
                                      wTqkv, woT, w1T, w2T,
                                      msk, maskp, x, xb, bq, bk, bv, bqkv);

  // QKV: BN=64, 1152 blocks; V section written directly to vt (fused vtrans)
  gemm_bt_t<64, 1, true><<<1152, 256, 0, stream>>>(
      xb, wTqkv, bqkv, qkv, vt, M_, 3 * D_, D_, 0, D_, SCALE_Q);
  flash_attn<<<(B_ * H_) * (S_ / 64), 256, 0, stream>>>(qkv, vt, maskp, ctx);
  // attn-out: split-K x4 -> 1536 blocks (6/CU), bf16 partials into Pattn
  gemm_bt_t<64, 4, false><<<1536, 256, 0, stream>>>(
      ctx, woT, nullptr, Pattn, nullptr, M_, D_, D_, 0, 0, 1.f);
  add_ln_comb<4, false, false><<<M_, 256, 0, stream>>>(
      xb, Pattn, bo, a1, be1, x1);
  // FF1: BN=128, 768 blocks, relu fused
  gemm_bt_t<128, 1, false><<<768, 256, 0, stream>>>(
      x1, w1T, b1, h1, nullptr, M_, DFF_, D_, 1, 0, 1.f);
  // FF2: split-K x4 -> 1536 blocks (6/CU), bf16 partials into Pff2
  gemm_bt_t<64, 4, false><<<1536, 256, 0, stream>>>(
      h1, w2T, nullptr, Pff2, nullptr, M_, D_, DFF_, 0, 0, 1.f);
  add_ln_comb<4, false, true><<<M_, 256, 0, stream>>>(
      x1, Pff2, b2, a2, be2, d_out);
}

// Round 13
// 288.384 us; speedup vs baseline: 1.0537x; 1.0537x over previous
//
#include <hip/hip_runtime.h>
#include <hip/hip_bf16.h>

// ---------------------------------------------------------------------------
// EncoderLayer: B=2 S=2048 D=768 H=12 DK=64 DFF=3072
// fp32 inputs/outputs; bf16 MFMA compute with fp32 accumulate.
// ---------------------------------------------------------------------------

typedef short short8 __attribute__((ext_vector_type(8)));
typedef float floatx4 __attribute__((ext_vector_type(4)));
typedef unsigned short ushort_t;
typedef ushort_t ushort4_t __attribute__((ext_vector_type(4)));

#define B_ 2
#define S_ 2048
#define D_ 768
#define H_ 12
#define DK_ 64
#define DFF_ 3072
#define M_ (B_ * S_)          // 4096 rows
#define RS_ (3 * D_)          // 2304 qkv row stride

#define LOG2E 1.44269504f
#define FMAX_SHIFT 16.0f      // fixed softmax shift (scores ~N(0,1), max ~6)

__device__ __forceinline__ float bf2f(ushort_t h) {
  union { unsigned int u; float f; } v; v.u = ((unsigned int)h) << 16; return v.f;
}
__device__ __forceinline__ ushort_t f2bf(float f) {
  union { float f; unsigned int u; } v; v.f = f;
  unsigned int u = v.u;
  unsigned int r = (u + 0x7fffu + ((u >> 16) & 1u)) >> 16;
  return (ushort_t)r;
}

// ---------------------------------------------------------------------------
// ALL prep in ONE launch:
//  [0,2304):      4 DxD transposes (wq,wk,wv->wTqkv; wo->woT)
//  [2304,4608):   w1 [768][3072] -> w1T
//  [4608,6912):   w2 [3072][768] -> w2T
//  [6912,8960):   mask int32 [q][kp] -> bias bf16 [q][kp-PERMUTED], log2 dom.
//  [8960,12032):  x fp32 -> xb bf16
//  [12032,12041): concat bq|bk|bv -> bqkv fp32
// kp-permutation per 64 window: pos f*32+lq*8+j holds kp=32f+16(j>>2)+4lq+(j&3)
// ---------------------------------------------------------------------------
__global__ __launch_bounds__(256) void prep_all(
    const float* __restrict__ wq, const float* __restrict__ wk,
    const float* __restrict__ wv, const float* __restrict__ wo,
    const float* __restrict__ w1, const float* __restrict__ w2,
    ushort_t* __restrict__ wTqkv, ushort_t* __restrict__ woT,
    ushort_t* __restrict__ w1T, ushort_t* __restrict__ w2T,
    const int* __restrict__ mask, ushort_t* __restrict__ maskp,
    const float* __restrict__ x, ushort_t* __restrict__ xb,
    const float* __restrict__ bq, const float* __restrict__ bk,
    const float* __restrict__ bv, float* __restrict__ bqkv) {
  __shared__ ushort_t t[32][33];
  const int blk = blockIdx.x, tid = threadIdx.x;
  if (blk < 6912) {
    const float* in; ushort_t* out; int K, N, bx, by;
    if (blk < 2304) {
      const int z = blk / 576, rr = blk % 576;
      in = (z == 0) ? wq : (z == 1) ? wk : (z == 2) ? wv : wo;
      out = (z < 3) ? (wTqkv + (size_t)z * D_ * D_) : woT;
      K = D_; N = D_; bx = rr % 24; by = rr / 24;
    } else if (blk < 4608) {
      const int rr = blk - 2304;
      in = w1; out = w1T; K = D_; N = DFF_; bx = rr % 96; by = rr / 96;
    } else {
      const int rr = blk - 4608;
      in = w2; out = w2T; K = DFF_; N = D_; bx = rr % 24; by = rr / 24;
    }
    const int nt = bx * 32, kt = by * 32;
    const int tx = tid & 31, ty = tid >> 5;
#pragma unroll
    for (int i = 0; i < 4; i++)
      t[ty + i * 8][tx] = f2bf(in[(size_t)(kt + ty + i * 8) * N + nt + tx]);
    __syncthreads();
#pragma unroll
    for (int i = 0; i < 4; i++)
      out[(size_t)(nt + ty + i * 8) * K + kt + tx] = t[tx][ty + i * 8];
  } else if (blk < 8960) {
    const int tt = (blk - 6912) * 256 + tid;        // one 8-elem chunk each
    const int q = tt >> 8;
    const int cc = tt & 255;
    const int k0 = (cc >> 3) * 64;
    const int g = cc & 7, f = g >> 2, lq = g & 3;
    const int* mrow = mask + (size_t)q * S_ + k0;
    const ushort_t cm = f2bf(-1.4427e9f);
    const ushort_t cu = f2bf(-FMAX_SHIFT * LOG2E);
    short8 o;
#pragma unroll
    for (int n2 = 0; n2 < 2; n2++)
#pragma unroll
      for (int r = 0; r < 4; r++) {
        const int kpl = 32 * f + 16 * n2 + 4 * lq + r;
        o[n2 * 4 + r] = (short)((mrow[kpl] == 0) ? cm : cu);
      }
    *(short8*)(maskp + (size_t)q * S_ + k0 + g * 8) = o;
  } else if (blk < 12032) {
    const int i = ((blk - 8960) * 256 + tid) * 4;
#pragma unroll
    for (int j = 0; j < 4; j++) xb[i + j] = f2bf(x[i + j]);
  } else {
    const int i = (blk - 12032) * 256 + tid;
    if (i < 3 * D_)
      bqkv[i] = (i < D_) ? bq[i] : (i < 2 * D_ ? bk[i - D_] : bv[i - 2 * D_]);
  }
}

// ---------------------------------------------------------------------------
// GEMM: BM=128, BN in {64,128}, BK=32, double-buffered LDS staging,
// XCD-aware 1-D grid decode. Z = split-K factor; Z>1 writes bf16 partial z
// to Cv + z*M*N (bias applied in combine).
// VOUT=true (QKV only): for n >= 2*D_ the result is V -> written directly to
// vt[bh][d][kp-PERMUTED] (fused vtrans); qkv V-section not written.
// ---------------------------------------------------------------------------
template <int BN, int Z, bool VOUT>
__global__ __launch_bounds__(256) void gemm_bt_t(
    const ushort_t* __restrict__ A, const ushort_t* __restrict__ Bt,
    const float* __restrict__ bias, void* __restrict__ Cv,
    ushort_t* __restrict__ vtout,
    int M, int N, int K, int relu, int qcols, float qscale) {
  constexpr int WN = (BN == 128) ? 2 : 1;
  constexpr int WM = 4 / WN;
  constexpr int FI = 128 / WM / 16;
  constexpr int FJ = BN / WN / 16;
  constexpr bool SPLIT = (Z > 1);
  __shared__ __align__(16) ushort_t Al[2][128 * 32];
  __shared__ __align__(16) ushort_t Bl[2][BN * 32];
  const int tid = threadIdx.x;
  const int w = tid >> 6, lane = tid & 63;
  const int wm = (WN == 2) ? (w >> 1) : w;
  const int wn = (WN == 2) ? (w & 1) : 0;
  const int lq = lane >> 4, lr = lane & 15;

  // XCD-aware decode
  const int NT_n = N / BN;
  const int mg = M >> 10;                 // m-tiles per XCD (M/128/8)
  const int lin = blockIdx.x;
  const int xcd = lin & 7, idx = lin >> 3;
  const int m_t = xcd * mg + idx / (NT_n * Z);
  const int rem = idx % (NT_n * Z);
  const int n_t = rem % NT_n;
  const int z   = rem / NT_n;
  const int m0 = m_t * 128, n0 = n_t * BN;

  int kBeg = 0, kEnd = K;
  if (SPLIT) { const int part = K / Z; kBeg = z * part; kEnd = kBeg + part; }
  const int NT = (kEnd - kBeg) / 32;

  auto stage = [&](int kt, int s) {
    const int k0 = kBeg + kt * 32;
#pragma unroll
    for (int i = 0; i < 2; i++) {
      const int base = (w * 2 + i) * 512;
      const int e = base + lane * 8;
      const int row = e >> 5, col = e & 31;
      __builtin_amdgcn_global_load_lds(
          (const __attribute__((address_space(1))) void*)(A + (size_t)(m0 + row) * K + k0 + col),
          (__attribute__((address_space(3))) void*)(&Al[s][base]), 16, 0, 0);
    }
#pragma unroll
    for (int i = 0; i < BN / 64; i++) {
      const int base = (w * (BN / 64) + i) * 512;
      const int e = base + lane * 8;
      const int row = e >> 5, col = e & 31;
      __builtin_amdgcn_global_load_lds(
          (const __attribute__((address_space(1))) void*)(Bt + (size_t)(n0 + row) * K + k0 + col),
          (__attribute__((address_space(3))) void*)(&Bl[s][base]), 16, 0, 0);
    }
  };

  floatx4 acc[FI][FJ];
#pragma unroll
  for (int i = 0; i < FI; i++)
#pragma unroll
    for (int j = 0; j < FJ; j++) acc[i][j] = (floatx4){0.f, 0.f, 0.f, 0.f};

  stage(0, 0);
  for (int kt = 0; kt < NT; kt++) {
    const int s = kt & 1;
    __syncthreads();                 // stage(kt) landed; buf s^1 reads done
    if (kt + 1 < NT) stage(kt + 1, s ^ 1);

    short8 af[FI], bf[FJ];
#pragma unroll
    for (int i = 0; i < FI; i++)
      af[i] = *(const short8*)&Al[s][(wm * (FI * 16) + i * 16 + lr) * 32 + lq * 8];
#pragma unroll
    for (int j = 0; j < FJ; j++)
      bf[j] = *(const short8*)&Bl[s][(wn * (FJ * 16) + j * 16 + lr) * 32 + lq * 8];
#pragma unroll
    for (int i = 0; i < FI; i++)
#pragma unroll
      for (int j = 0; j < FJ; j++)
        acc[i][j] = __builtin_amdgcn_mfma_f32_16x16x32_bf16(af[i], bf[j], acc[i][j], 0, 0, 0);
  }

#pragma unroll
  for (int i = 0; i < FI; i++) {
    const int m = m0 + wm * (FI * 16) + i * 16 + lq * 4;
#pragma unroll
    for (int j = 0; j < FJ; j++) {
      const int n = n0 + wn * (FJ * 16) + j * 16 + lr;
      if (SPLIT) {
        ushort_t* P = (ushort_t*)Cv + (size_t)z * M * N;
#pragma unroll
        for (int r = 0; r < 4; r++)
          P[(size_t)(m + r) * N + n] = f2bf(acc[i][j][r]);
      } else if (VOUT && n >= 2 * D_) {
        // fused vtrans: element (kp=m+r, d) of head h -> vt permuted layout
        const int h = (n - 2 * D_) >> 6, d = (n - 2 * D_) & 63;
        const int bh = (m >> 11) * H_ + h;
        const int kp = m & (S_ - 1);
        const int kw = kp & 63;     // kw&3==0 since m%4==0
        const int pos = (kp & ~63) + ((kw >> 5) << 5) + (((kw >> 2) & 3) << 3)
                      + (((kw >> 4) & 1) << 2);
        const float bv = bias[n];
        ushort4_t o;
#pragma unroll
        for (int r = 0; r < 4; r++) o[r] = f2bf(acc[i][j][r] + bv);
        *(ushort4_t*)(vtout + ((size_t)bh * DK_ + d) * S_ + pos) = o;
      } else {
        const float bv = bias[n];
#pragma unroll
        for (int r = 0; r < 4; r++) {
          float v = acc[i][j][r] + bv;
          if (n < qcols) v *= qscale;
          if (relu) v = v > 0.f ? v : 0.f;
          ((ushort_t*)Cv)[(size_t)(m + r) * N + n] = f2bf(v);
        }
      }
    }
  }
}

// ---------------------------------------------------------------------------
// Flash attention v8 — 2x2 wave split (q-half x kp-half): wave (wq,wk) does
// 32q x 32kp, halving redundant K/V LDS reads. Fixed-shift softmax; mask bias
// staged in LDS and folded into MFMA C-init; li via all-ones MFMA. Cross-wk
// pair reduction via LDS at the end. 768 blocks, 4 waves, 48 KB LDS.
// (v9's register-direct global bias loads regressed — scattered 4KB-strided
// rows, 64 lines/instr; LDS staging is the verified-faster path.)
// ---------------------------------------------------------------------------
__global__ __launch_bounds__(256, 3) void flash_attn(
    const ushort_t* __restrict__ qkv, const ushort_t* __restrict__ vt,
    const ushort_t* __restrict__ maskp, ushort_t* __restrict__ ctx) {
  __shared__ __align__(16) ushort_t lds[2][3][64 * 64];   // [buf][K,V,M] 48 KB
  const int tid = threadIdx.x;
  const int w = tid >> 6, lane = tid & 63;
  const int wq = w >> 1, wk = w & 1;
  const int lq = lane >> 4, lr = lane & 15;
  const int blk = blockIdx.x;
  const int bh = blk % (B_ * H_), qb = blk / (B_ * H_);
  const int b = bh / H_, h = bh % H_;
  const int q0 = qb * 64;
  const ushort_t* qbase = qkv + (size_t)(b * S_) * RS_ + h * DK_;
  const ushort_t* kbase = qbase + D_;
  const ushort_t* vtb   = vt + (size_t)bh * DK_ * S_;
  const ushort_t* mb    = maskp + (size_t)q0 * S_;

  // Q fragments: wave covers q = q0 + wq*32 + qf*16 + lr (pre-scaled log2e/8)
  short8 qfr[2][2];
#pragma unroll
  for (int qf = 0; qf < 2; qf++)
#pragma unroll
    for (int f = 0; f < 2; f++)
      qfr[qf][f] = *(const short8*)(
          qbase + (size_t)(q0 + wq * 32 + qf * 16 + lr) * RS_ + f * 32 + lq * 8);

  auto stage = [&](int k0, int s) {
#pragma unroll
    for (int i = 0; i < 2; i++) {
      const int id = i * 256 + tid;
      const int row = id >> 3;
      const int cc = ((id & 7) ^ (row & 7)) * 8;
      const int dbase = (i * 256 + w * 64) * 8;    // wave-uniform LDS base
      __builtin_amdgcn_global_load_lds(
          (const __attribute__((address_space(1))) void*)(kbase + (size_t)(k0 + row) * RS_ + cc),
          (__attribute__((address_space(3))) void*)(&lds[s][0][dbase]), 16, 0, 0);
      __builtin_amdgcn_global_load_lds(
          (const __attribute__((address_space(1))) void*)(vtb + (size_t)row * S_ + k0 + cc),
          (__attribute__((address_space(3))) void*)(&lds[s][1][dbase]), 16, 0, 0);
      __builtin_amdgcn_global_load_lds(
          (const __attribute__((address_space(1))) void*)(mb + (size_t)row * S_ + k0 + cc),
          (__attribute__((address_space(3))) void*)(&lds[s][2][dbase]), 16, 0, 0);
    }
  };

  floatx4 oacc[2][4], oli[2];
#pragma unroll
  for (int qf = 0; qf < 2; qf++) {
    oli[qf] = (floatx4){0.f, 0.f, 0.f, 0.f};
#pragma unroll
    for (int dt = 0; dt < 4; dt++) oacc[qf][dt] = (floatx4){0.f, 0.f, 0.f, 0.f};
  }
  short8 ones;
#pragma unroll
  for (int j = 0; j < 8; j++) ones[j] = (short)0x3F80;   // bf16 1.0

  stage(0, 0);
  __syncthreads();

  const int sw8 = lr & 7;
  const int c0 = (lq ^ sw8) * 8;              // K chunk, k-half 0
  const int c1 = ((4 + lq) ^ sw8) * 8;        // K chunk, k-half 1
  const int cW = ((4 * wk + lq) ^ sw8) * 8;   // wave's kp-window chunk (V, bias)

  constexpr int NT = S_ / 64;
  for (int t = 0; t < NT; t++) {
    const int s = t & 1;
    if (t + 1 < NT) stage((t + 1) * 64, s ^ 1);

    const ushort_t* kl = &lds[s][0][0];
    const ushort_t* vl = &lds[s][1][0];
    const ushort_t* ml = &lds[s][2][0];

    // mask bias as MFMA C-init: bb[4*n2+r] -> sacc[n2][r]
    floatx4 sacc[2][2];
#pragma unroll
    for (int qf = 0; qf < 2; qf++) {
      const short8 bb = *(const short8*)(ml + (wq * 32 + qf * 16 + lr) * 64 + cW);
#pragma unroll
      for (int n2 = 0; n2 < 2; n2++)
#pragma unroll
        for (int r = 0; r < 4; r++)
          sacc[qf][n2][r] = bf2f((ushort_t)bb[n2 * 4 + r]);
    }

    // QK^T: wave's kp strips (2wk+n2)
#pragma unroll
    for (int n2 = 0; n2 < 2; n2++) {
      const int krow = ((2 * wk + n2) * 16 + lr) * 64;
      short8 a0 = *(const short8*)(kl + krow + c0);
      short8 a1 = *(const short8*)(kl + krow + c1);
#pragma unroll
      for (int qf = 0; qf < 2; qf++) {
        sacc[qf][n2] = __builtin_amdgcn_mfma_f32_16x16x32_bf16(a0, qfr[qf][0], sacc[qf][n2], 0, 0, 0);
        sacc[qf][n2] = __builtin_amdgcn_mfma_f32_16x16x32_bf16(a1, qfr[qf][1], sacc[qf][n2], 0, 0, 0);
      }
    }

    // p = exp2(s) (bias already inside); pack into PV B-fragments
    short8 pf[2];
#pragma unroll
    for (int qf = 0; qf < 2; qf++) {
      union { __hip_bfloat162 h2[4]; short8 v; } u;
#pragma unroll
      for (int jj = 0; jj < 4; jj++) {
        const int e0 = jj * 2, e1 = jj * 2 + 1;
        float2 p2;
        p2.x = __builtin_amdgcn_exp2f(sacc[qf][e0 >> 2][e0 & 3]);
        p2.y = __builtin_amdgcn_exp2f(sacc[qf][e1 >> 2][e1 & 3]);
        u.h2[jj] = __float22bfloat162_rn(p2);
      }
      pf[qf] = u.v;
    }

    // PV (O^T) + li via ones-MFMA
#pragma unroll
    for (int dt = 0; dt < 4; dt++) {
      const short8 vfr = *(const short8*)(vl + (dt * 16 + lr) * 64 + cW);
#pragma unroll
      for (int qf = 0; qf < 2; qf++)
        oacc[qf][dt] = __builtin_amdgcn_mfma_f32_16x16x32_bf16(vfr, pf[qf], oacc[qf][dt], 0, 0, 0);
    }
#pragma unroll
    for (int qf = 0; qf < 2; qf++)
      oli[qf] = __builtin_amdgcn_mfma_f32_16x16x32_bf16(ones, pf[qf], oli[qf], 0, 0, 0);

    __syncthreads();
  }

  // cross-wk pair reduction via LDS (lane-matched; stride 37 spreads banks)
  float* ex = (float*)&lds[0][0][0];     // [2 wq][64 lane][37] = 18.9 KB
  if (wk == 1) {
    float* dst = ex + (size_t)(wq * 64 + lane) * 37;
#pragma unroll
    for (int qf = 0; qf < 2; qf++)
#pragma unroll
      for (int dt = 0; dt < 4; dt++)
#pragma unroll
        for (int r = 0; r < 4; r++)
          dst[qf * 16 + dt * 4 + r] = oacc[qf][dt][r];
    dst[32] = oli[0][0];
    dst[33] = oli[1][0];
  }
  __syncthreads();
  if (wk == 0) {
    const float* src = ex + (size_t)(wq * 64 + lane) * 37;
#pragma unroll
    for (int qf = 0; qf < 2; qf++)
#pragma unroll
      for (int dt = 0; dt < 4; dt++)
#pragma unroll
        for (int r = 0; r < 4; r++)
          oacc[qf][dt][r] += src[qf * 16 + dt * 4 + r];
    const float inv0 = 1.f / (oli[0][0] + src[32] + 1e-30f);
    const float inv1 = 1.f / (oli[1][0] + src[33] + 1e-30f);
#pragma unroll
    for (int qf = 0; qf < 2; qf++) {
      const float inv = qf ? inv1 : inv0;
      const size_t row = (size_t)(b * S_ + q0 + wq * 32 + qf * 16 + lr) * D_ + h * DK_;
#pragma unroll
      for (int dt = 0; dt < 4; dt++) {
        ushort4_t o;
#pragma unroll
        for (int r = 0; r < 4; r++) o[r] = f2bf(oacc[qf][dt][r] * inv);
        *(ushort4_t*)(ctx + row + dt * 16 + lq * 4) = o;
      }
    }
  }
}

// ---------------------------------------------------------------------------
// out = alpha * (v - mean)/(std_unbiased + eps) + beta, row = 768,
// where v = x + (sum_{p<NP} P[p] + colbias), P bf16 split-K partials at
// stride M*D. Vectorized: 192 threads x 4 consecutive elements (ushort4 /
// float4 loads). XF: x fp32 (else bf16). OF: out fp32 (else bf16).
// ---------------------------------------------------------------------------
template <int NP, bool XF, bool OF>
__global__ __launch_bounds__(192) void add_ln_comb(
    const void* __restrict__ xv, const ushort_t* __restrict__ P,
    const float* __restrict__ cb,
    const float* __restrict__ alpha, const float* __restrict__ beta,
    void* __restrict__ outv) {
  const int row = blockIdx.x, tid = threadIdx.x;
  const int w = tid >> 6, lane = tid & 63;
  __shared__ float red[6];
  const size_t base = (size_t)row * D_ + tid * 4;
  float v[4];
  {
    float xv4[4];
    if (XF) {
      const float4 xx = *(const float4*)((const float*)xv + base);
      xv4[0] = xx.x; xv4[1] = xx.y; xv4[2] = xx.z; xv4[3] = xx.w;
    } else {
      const ushort4_t xx = *(const ushort4_t*)((const ushort_t*)xv + base);
#pragma unroll
      for (int r = 0; r < 4; r++) xv4[r] = bf2f(xx[r]);
    }
    const float4 cb4 = *(const float4*)(cb + tid * 4);
    float ps[4] = {cb4.x, cb4.y, cb4.z, cb4.w};
#pragma unroll
    for (int p = 0; p < NP; p++) {
      const ushort4_t pp = *(const ushort4_t*)(P + base + (size_t)p * M_ * D_);
#pragma unroll
      for (int r = 0; r < 4; r++) ps[r] += bf2f(pp[r]);
    }
#pragma unroll
    for (int r = 0; r < 4; r++) v[r] = xv4[r] + ps[r];
  }
  float s = (v[0] + v[1]) + (v[2] + v[3]);
#pragma unroll
  for (int off = 1; off < 64; off <<= 1) s += __shfl_xor(s, off);
  if (lane == 0) red[w] = s;
  __syncthreads();
  const float mean = (red[0] + red[1] + red[2]) / (float)D_;
  float d = 0.f;
#pragma unroll
  for (int r = 0; r < 4; r++) { const float t = v[r] - mean; d += t * t; }
#pragma unroll
  for (int off = 1; off < 64; off <<= 1) d += __shfl_xor(d, off);
  if (lane == 0) red[3 + w] = d;
  __syncthreads();
  const float var = (red[3] + red[4] + red[5]) / (float)(D_ - 1);
  const float inv = 1.f / (sqrtf(var) + 1e-6f);
  const float a = alpha[0] * inv, bt = beta[0];
  if (OF) {
    float4 o;
    o.x = a * (v[0] - mean) + bt;  o.y = a * (v[1] - mean) + bt;
    o.z = a * (v[2] - mean) + bt;  o.w = a * (v[3] - mean) + bt;
    *(float4*)((float*)outv + base) = o;
  } else {
    ushort4_t o;
#pragma unroll
    for (int r = 0; r < 4; r++) o[r] = f2bf(a * (v[r] - mean) + bt);
    *(ushort4_t*)((ushort_t*)outv + base) = o;
  }
}

// ---------------------------------------------------------------------------
// launch
// ---------------------------------------------------------------------------
extern "C" void kernel_launch(void* const* d_in, const int* in_sizes, int n_in,
                              void* d_out, int out_size, void* d_ws, size_t ws_size,
                              hipStream_t stream) {
  const float* x   = (const float*)d_in[0];
  const float* wq  = (const float*)d_in[1];
  const float* bq  = (const float*)d_in[2];
  const float* wk  = (const float*)d_in[3];
  const float* bk  = (const float*)d_in[4];
  const float* wv  = (const float*)d_in[5];
  const float* bv  = (const float*)d_in[6];
  const float* wo  = (const float*)d_in[7];
  const float* bo  = (const float*)d_in[8];
  const float* w1  = (const float*)d_in[9];
  const float* b1  = (const float*)d_in[10];
  const float* w2  = (const float*)d_in[11];
  const float* b2  = (const float*)d_in[12];
  const float* a1  = (const float*)d_in[13];
  const float* be1 = (const float*)d_in[14];
  const float* a2  = (const float*)d_in[15];
  const float* be2 = (const float*)d_in[16];
  const int*   msk = (const int*)d_in[17];

  // workspace layout in ushort units; all offsets multiple of 8 (16B aligned)
  const size_t E_xb    = 0;
  const size_t E_wTqkv = E_xb    + (size_t)M_ * D_;
  const size_t E_woT   = E_wTqkv + (size_t)3 * D_ * D_;
  const size_t E_w1T   = E_woT   + (size_t)D_ * D_;
  const size_t E_w2T   = E_w1T   + (size_t)DFF_ * D_;
  const size_t E_bqkv  = E_w2T   + (size_t)D_ * DFF_;
  const size_t E_qkv   = E_bqkv  + (size_t)2 * 3 * D_;
  const size_t E_ctx   = E_qkv   + (size_t)M_ * 3 * D_;
  const size_t E_attn  = E_ctx   + (size_t)M_ * D_;
  const size_t E_x1    = E_attn  + (size_t)M_ * D_;
  const size_t E_h1    = E_x1    + (size_t)M_ * D_;       // h1 [M][DFF] (12.58M)
  const size_t E_ff    = E_h1    + (size_t)M_ * DFF_;
  const size_t E_total = E_ff    + (size_t)M_ * D_;
  if (ws_size < E_total * sizeof(ushort_t)) return;

  ushort_t* ws    = (ushort_t*)d_ws;
  ushort_t* xb    = ws + E_xb;
  ushort_t* wTqkv = ws + E_wTqkv;
  ushort_t* woT   = ws + E_woT;
  ushort_t* w1T   = ws + E_w1T;
  ushort_t* w2T   = ws + E_w2T;
  float*    bqkv  = (float*)(ws + E_bqkv);
  ushort_t* qkv   = ws + E_qkv;
  ushort_t* ctx   = ws + E_ctx;
  ushort_t* x1    = ws + E_x1;
  ushort_t* h1    = ws + E_h1;
  // Overlays (lifetimes disjoint):
  //  maskp (4.19M) + vt (3.15M) live in h1 region until flash done.
  //  Pattn (2 x M x D bf16 = 6.29M ushorts) = h1 region after flash,
  //    dead once FF1 writes h1.
  //  Pff2 (6.29M ushorts) = qkv region after qkv/ctx dead.
  ushort_t* maskp = ws + E_h1;
  ushort_t* vt    = ws + E_h1 + (size_t)S_ * S_;
  ushort_t* Pattn = ws + E_h1;
  ushort_t* Pff2  = ws + E_qkv;

  const float SCALE_Q = 0.125f * LOG2E;   // log2-domain scores

  prep_all<<<12041, 256, 0, stream>>>(wq, wk, wv, wo, w1, w2,
                                      wTqkv, woT, w1T, w2T,
                                      msk, maskp, x, xb, bq, bk, bv, bqkv);

  // QKV: BN=64, 1152 blocks; V section written directly to vt (fused vtrans)
  gemm_bt_t<64, 1, true><<<1152, 256, 0, stream>>>(
      xb, wTqkv, bqkv, qkv, vt, M_, 3 * D_, D_, 0, D_, SCALE_Q);
  flash_attn<<<(B_ * H_) * (S_ / 64), 256, 0, stream>>>(qkv, vt, maskp, ctx);
  // attn-out: split-K x2, 768 blocks, bf16 partials into Pattn
  gemm_bt_t<64, 2, false><<<768, 256, 0, stream>>>(
      ctx, woT, nullptr, Pattn, nullptr, M_, D_, D_, 0, 0, 1.f);
  add_ln_comb<2, false, false><<<M_, 192, 0, stream>>>(
      xb, Pattn, bo, a1, be1, x1);
  // FF1: BN=128, 768 blocks, relu fused
  gemm_bt_t<128, 1, false><<<768, 256, 0, stream>>>(
      x1, w1T, b1, h1, nullptr, M_, DFF_, D_, 1, 0, 1.f);
  // FF2: split-K x2, 768 blocks, bf16 partials into Pff2
  gemm_bt_t<64, 2, false><<<768, 256, 0, stream>>>(
      h1, w2T, nullptr, Pff2, nullptr, M_, D_, DFF_, 0, 0, 1.f);
  add_ln_comb<2, false, true><<<M_, 192, 0, stream>>>(
      x1, Pff2, b2, a2, be2, d_out);
}